// Round 10
// baseline (688.687 us; speedup 1.0000x reference)
//
#include <hip/hip_runtime.h>
#include <stdint.h>

// NNAKF round 10: wave specialization. r9 proved replicated per-wave Kalman
// work is the poison (2 waves/SIMD doubled it -> regression). Now waves 0-2 =
// LSTM waves (12 gate-tiles GEMM + 3 pointwise cells/thread), wave 3 = Kalman
// wave (fc -> sigma -> Qdot -> update -> predict -> In, all 4 batches SIMT).
// Kalman chain runs CONCURRENTLY with GEMM on other SIMDs. 2 barriers/step:
// B1 publishes h(t), B2 publishes In(t+1). w2 recomputes group 7 redundantly
// (same thread, same values) to keep unrolls branch-free.

#define DTc  0.1f
#define Q0V  0.01f      // PROCESS_NOISE_STD^2
#define RV   0.25f      // MEAS_NOISE_STD^2

typedef __bf16 bf16x8 __attribute__((ext_vector_type(8)));
typedef float  f32x4  __attribute__((ext_vector_type(4)));

__device__ __forceinline__ unsigned short f2bf(float f) {
    union { float f; unsigned int ui; } c; c.f = f;
    unsigned int u = c.ui;
    return (unsigned short)((u + 0x7FFFu + ((u >> 16) & 1u)) >> 16);   // RNE
}
__device__ __forceinline__ bf16x8 cvt8(float4 a, float4 b) {
    union { unsigned short us[8]; bf16x8 v; } r;
    r.us[0] = f2bf(a.x); r.us[1] = f2bf(a.y); r.us[2] = f2bf(a.z); r.us[3] = f2bf(a.w);
    r.us[4] = f2bf(b.x); r.us[5] = f2bf(b.y); r.us[6] = f2bf(b.z); r.us[7] = f2bf(b.w);
    return r.v;
}
__device__ __forceinline__ float rcpf(float x)  { return __builtin_amdgcn_rcpf(x); }
__device__ __forceinline__ float sigmf(float x) { return rcpf(1.0f + __expf(-x)); }
__device__ __forceinline__ float tanhf_(float x){ return 1.0f - 2.0f * rcpf(__expf(2.0f * x) + 1.0f); }

#define QP_ROT2  0x4E   // quad_perm [2,3,0,1]
#define QP_BC0   0x00   // quad broadcast lane 0
#define QP_BC1   0x55   // quad broadcast lane 1
template<int CTRL>
__device__ __forceinline__ float dppf(float x) {
    return __builtin_bit_cast(float,
        __builtin_amdgcn_update_dpp(0, __builtin_bit_cast(int, x), CTRL, 0xF, 0xF, true));
}

__global__ __launch_bounds__(256, 1) void nnakf_kernel(
    const float* __restrict__ meas,   // [1024][512][2] f32
    const float* __restrict__ Qt,     // [10][4][4]
    const float* __restrict__ Wih,    // [512][2]
    const float* __restrict__ Whh,    // [512][128]
    const float* __restrict__ bih,    // [512]
    const float* __restrict__ bhh,    // [512]
    const float* __restrict__ Wfc,    // [10][128]
    const float* __restrict__ bfc,    // [10]
    float* __restrict__ out)          // [1024][512][4] f32
{
    __shared__ float          meas_s[4 * 1024];   // [b][t*2+c]
    __shared__ unsigned short hbuf[640];          // h bf16, [b] stride 160
    __shared__ float          sig_s[64];          // [q*16+n], wave-3 private RT
    __shared__ float2         inbuf[4];           // In per batch

    const int tid  = threadIdx.x;
    const int w    = tid >> 6;          // wave 0..3 (3 = Kalman wave)
    const int lane = tid & 63;
    const int idx  = lane & 15;
    const int q    = lane >> 4;         // batch
    const int j    = lane & 3;          // Kalman column
    const int bg0  = blockIdx.x * 4;

    // ---- cooperative meas load ----
    {
        const float4* g4 = (const float4*)(meas + (size_t)bg0 * 1024);
        float4* ms4 = (float4*)meas_s;
        for (int k = tid; k < 1024; k += 256) ms4[k] = g4[k];
    }

    // ---- per-role weights ----
    bf16x8 wf[3][4][4];     // LSTM waves: [group][gate][kstep]
    f32x4  biasC[3][4];
    float2 wihr[3][4];
    int    hoff[3];         // pointwise h-write LDS offsets
    bf16x8 fcf[4];          // Kalman wave
    float  bfc_r = 0.0f;
    float  qreg[10][4];

    if (w < 3) {
        const float4* whh4 = (const float4*)Whh;
        #pragma unroll
        for (int gg = 0; gg < 3; ++gg) {
            int g = w * 3 + gg; if (g > 7) g = 7;   // w2 redoes group 7 (benign)
            hoff[gg] = q * 160 + g * 16 + idx;
            #pragma unroll
            for (int gt = 0; gt < 4; ++gt) {
                const int n = gt * 128 + g * 16 + idx;
                const float bb = bih[n] + bhh[n];
                biasC[gg][gt] = (f32x4){bb, bb, bb, bb};
                wihr[gg][gt] = ((const float2*)Wih)[n];
                #pragma unroll
                for (int s = 0; s < 4; ++s) {
                    float4 u0 = whh4[n * 32 + s * 8 + q * 2];
                    float4 u1 = whh4[n * 32 + s * 8 + q * 2 + 1];
                    wf[gg][gt][s] = cvt8(u0, u1);   // B[k=s*32+q*8+e][n]
                }
            }
        }
    } else {
        #pragma unroll
        for (int s = 0; s < 4; ++s) {
            float4 u0 = make_float4(0.f, 0.f, 0.f, 0.f), u1 = u0;
            if (idx < 10) {
                u0 = ((const float4*)Wfc)[idx * 32 + s * 8 + q * 2];
                u1 = ((const float4*)Wfc)[idx * 32 + s * 8 + q * 2 + 1];
            }
            fcf[s] = cvt8(u0, u1);
        }
        bfc_r = (idx < 10) ? bfc[idx] : 0.0f;
        #pragma unroll
        for (int n = 0; n < 10; ++n)
            #pragma unroll
            for (int r = 0; r < 4; ++r) qreg[n][r] = Qt[n * 16 + r * 4 + j];
    }

    // ---- persistent state ----
    float P0 = (j == 0) ? 1.f : 0.f, P1 = (j == 1) ? 1.f : 0.f;
    float P2 = (j == 2) ? 1.f : 0.f, P3 = (j == 3) ? 1.f : 0.f;
    float x0 = 0.f, x1 = 0.f, x2 = 0.f, x3 = 0.f;
    float cst[3] = {0.f, 0.f, 0.f};
    float ppc0, ppc1, ppc2, ppc3, xp0, xp1, inn0, inn1, In0, In1;
    f32x4 acc[3][4];

    #define PREDICT(TT)                                                          \
    {                                                                            \
        const float fp0 = P0 + DTc * P2, fp1 = P1 + DTc * P3;                    \
        const float d0 = dppf<QP_ROT2>(P0), d1 = dppf<QP_ROT2>(P1);              \
        const float d2 = dppf<QP_ROT2>(P2), d3 = dppf<QP_ROT2>(P3);              \
        const float fq0 = d0 + DTc * d2, fq1 = d1 + DTc * d3;                    \
        const bool jl2 = (j < 2);                                                \
        ppc0 = fp0 + (jl2 ? DTc * fq0 : 0.f) + ((j == 0) ? Q0V : 0.f);           \
        ppc1 = fp1 + (jl2 ? DTc * fq1 : 0.f) + ((j == 1) ? Q0V : 0.f);           \
        ppc2 = P2  + (jl2 ? DTc * d2  : 0.f) + ((j == 2) ? Q0V : 0.f);           \
        ppc3 = P3  + (jl2 ? DTc * d3  : 0.f) + ((j == 3) ? Q0V : 0.f);           \
        xp0 = x0 + DTc * x2; xp1 = x1 + DTc * x3;                                \
        const float2 zz = *(const float2*)&meas_s[q * 1024 + 2 * (TT)];          \
        inn0 = zz.x - xp0; inn1 = zz.y - xp1;                                    \
        const float s000 = dppf<QP_BC0>(ppc0) + RV;                              \
        const float s011 = dppf<QP_BC1>(ppc1) + RV;                              \
        In0 = inn0 * inn0 * rcpf(s000);                                          \
        In1 = inn1 * inn1 * rcpf(s011);                                          \
    }

    __syncthreads();   // meas_s ready

    if (w == 3) {
        PREDICT(0)
        if (idx == 0) inbuf[q] = make_float2(In0, In1);
    } else {
        #pragma unroll
        for (int gg = 0; gg < 3; ++gg)
            #pragma unroll
            for (int gt = 0; gt < 4; ++gt)
                acc[gg][gt] = biasC[gg][gt];   // h(-1)=0 -> gates = bias
    }
    __syncthreads();   // inbuf(0) ready

    for (int t = 0; t < 512; ++t) {
        // ======== segment A: pointwise LSTM(t) on waves 0-2 ==================
        if (w < 3) {
            const float2 inq = inbuf[q];
            #pragma unroll
            for (int gg = 0; gg < 3; ++gg) {
                float pre[4];
                #pragma unroll
                for (int gt = 0; gt < 4; ++gt)
                    pre[gt] = acc[gg][gt][0] + inq.x * wihr[gg][gt].x + inq.y * wihr[gg][gt].y;
                const float cn = sigmf(pre[1]) * cst[gg] + sigmf(pre[0]) * tanhf_(pre[2]);
                const float hn = sigmf(pre[3]) * tanhf_(cn);
                cst[gg] = cn;
                hbuf[hoff[gg]] = f2bf(hn);
            }
        }
        __syncthreads();   // B1: h(t) published

        // ======== segment B: GEMM (w0-2)  ||  Kalman chain (w3) ==============
        if (w == 3) {
            bf16x8 af[4];
            #pragma unroll
            for (int s = 0; s < 4; ++s)
                af[s] = __builtin_bit_cast(bf16x8,
                            *(const uint4*)&hbuf[(idx >> 2) * 160 + s * 32 + q * 8]);
            f32x4 f0 = (f32x4){0.f, 0.f, 0.f, 0.f};
            f32x4 f1 = (f32x4){0.f, 0.f, 0.f, 0.f};
            f0 = __builtin_amdgcn_mfma_f32_16x16x32_bf16(af[0], fcf[0], f0, 0, 0, 0);
            f1 = __builtin_amdgcn_mfma_f32_16x16x32_bf16(af[1], fcf[1], f1, 0, 0, 0);
            f0 = __builtin_amdgcn_mfma_f32_16x16x32_bf16(af[2], fcf[2], f0, 0, 0, 0);
            f1 = __builtin_amdgcn_mfma_f32_16x16x32_bf16(af[3], fcf[3], f1, 0, 0, 0);
            const f32x4 facc = f0 + f1;
            const float sg = sigmf(facc[0] + bfc_r);   // sigma[batch q][n=idx]
            if (idx < 10) sig_s[q * 16 + idx] = sg;
            float sn[10];   // same-wave DS ordering
            #pragma unroll
            for (int n = 0; n < 10; ++n) sn[n] = sig_s[q * 16 + n];
            float a0 = 0.f, a1 = 0.f, a2 = 0.f, a3 = 0.f;
            float e0 = 0.f, e1 = 0.f, e2 = 0.f, e3 = 0.f;
            #pragma unroll
            for (int n = 0; n < 5; ++n) {
                a0 += sn[n] * qreg[n][0]; a1 += sn[n] * qreg[n][1];
                a2 += sn[n] * qreg[n][2]; a3 += sn[n] * qreg[n][3];
            }
            #pragma unroll
            for (int n = 5; n < 10; ++n) {
                e0 += sn[n] * qreg[n][0]; e1 += sn[n] * qreg[n][1];
                e2 += sn[n] * qreg[n][2]; e3 += sn[n] * qreg[n][3];
            }
            const float pc0 = ppc0 + a0 + e0;   // P_pred[:,j]
            const float pc1 = ppc1 + a1 + e1;
            const float pc2 = ppc2 + a2 + e2;
            const float pc3 = ppc3 + a3 + e3;
            const float ph00 = dppf<QP_BC0>(pc0), ph01 = dppf<QP_BC1>(pc0);
            const float ph10 = dppf<QP_BC0>(pc1), ph11 = dppf<QP_BC1>(pc1);
            const float ph20 = dppf<QP_BC0>(pc2), ph21 = dppf<QP_BC1>(pc2);
            const float ph30 = dppf<QP_BC0>(pc3), ph31 = dppf<QP_BC1>(pc3);
            const float s00 = ph00 + RV, s01 = ph01, s10 = ph10, s11 = ph11 + RV;
            const float rdet = rcpf(s00 * s11 - s01 * s10);
            const float u0 = rdet * (s11 * inn0 - s01 * inn1);
            const float u1 = rdet * (s00 * inn1 - s10 * inn0);
            x0 = xp0 + ph00 * u0 + ph01 * u1;
            x1 = xp1 + ph10 * u0 + ph11 * u1;
            x2 = x2  + ph20 * u0 + ph21 * u1;
            x3 = x3  + ph30 * u0 + ph31 * u1;
            const float w0 = rdet * (s11 * pc0 - s01 * pc1);
            const float w1 = rdet * (s00 * pc1 - s10 * pc0);
            P0 = pc0 - ph00 * w0 - ph01 * w1;
            P1 = pc1 - ph10 * w0 - ph11 * w1;
            P2 = pc2 - ph20 * w0 - ph21 * w1;
            P3 = pc3 - ph30 * w0 - ph31 * w1;
            if (idx == 0) {
                float4* o = (float4*)out;
                o[(size_t)(bg0 + q) * 512 + t] = make_float4(x0, x1, x2, x3);
            }
            const int tn = (t < 511) ? t + 1 : 511;
            PREDICT(tn)
            if (idx == 0) inbuf[q] = make_float2(In0, In1);
        } else {
            bf16x8 af[4];
            #pragma unroll
            for (int s = 0; s < 4; ++s)
                af[s] = __builtin_bit_cast(bf16x8,
                            *(const uint4*)&hbuf[(idx >> 2) * 160 + s * 32 + q * 8]);
            #pragma unroll
            for (int s = 0; s < 4; ++s)
                #pragma unroll
                for (int gg = 0; gg < 3; ++gg)
                    #pragma unroll
                    for (int gt = 0; gt < 4; ++gt)
                        acc[gg][gt] = __builtin_amdgcn_mfma_f32_16x16x32_bf16(
                            af[s], wf[gg][gt][s],
                            (s == 0) ? biasC[gg][gt] : acc[gg][gt], 0, 0, 0);
        }
        __syncthreads();   // B2: In(t+1) + acc(t+1) ready for next pointwise
    }
}

extern "C" void kernel_launch(void* const* d_in, const int* in_sizes, int n_in,
                              void* d_out, int out_size, void* d_ws, size_t ws_size,
                              hipStream_t stream) {
    (void)in_sizes; (void)n_in; (void)out_size; (void)d_ws; (void)ws_size;
    nnakf_kernel<<<256, 256, 0, stream>>>(
        (const float*)d_in[0],  // measurements
        (const float*)d_in[1],  // Q_tilde
        (const float*)d_in[2],  // W_ih
        (const float*)d_in[3],  // W_hh
        (const float*)d_in[4],  // b_ih
        (const float*)d_in[5],  // b_hh
        (const float*)d_in[6],  // W_fc
        (const float*)d_in[7],  // b_fc
        (float*)d_out);
}

// Round 11
// 488.706 us; speedup vs baseline: 1.4092x; 1.4092x over previous
//
#include <hip/hip_runtime.h>
#include <stdint.h>

// NNAKF round 11: slim uniform waves + single-wave Kalman.
// 512 threads = 8 waves (2/SIMD). Every wave: 4 gate-tiles GEMM (16 MFMA) +
// 1 pointwise cell/thread (VGPR ~210, r9 showed 128 base -> no spills).
// ONLY wave 0 runs the Kalman tail (fc -> sigma -> Qdot -> update -> predict
// -> In) for all 4 batches SIMT; In broadcast via LDS (r10-proven). Partner
// wave on SIMD0 hides w0's chain stalls. 2 barriers/step (h publish, In
// publish); hbuf needs no ping-pong under this barrier pattern.

#define DTc  0.1f
#define Q0V  0.01f      // PROCESS_NOISE_STD^2
#define RV   0.25f      // MEAS_NOISE_STD^2

typedef __bf16 bf16x8 __attribute__((ext_vector_type(8)));
typedef float  f32x4  __attribute__((ext_vector_type(4)));

__device__ __forceinline__ unsigned short f2bf(float f) {
    union { float f; unsigned int ui; } c; c.f = f;
    unsigned int u = c.ui;
    return (unsigned short)((u + 0x7FFFu + ((u >> 16) & 1u)) >> 16);   // RNE
}
__device__ __forceinline__ bf16x8 cvt8(float4 a, float4 b) {
    union { unsigned short us[8]; bf16x8 v; } r;
    r.us[0] = f2bf(a.x); r.us[1] = f2bf(a.y); r.us[2] = f2bf(a.z); r.us[3] = f2bf(a.w);
    r.us[4] = f2bf(b.x); r.us[5] = f2bf(b.y); r.us[6] = f2bf(b.z); r.us[7] = f2bf(b.w);
    return r.v;
}
__device__ __forceinline__ float rcpf(float x)  { return __builtin_amdgcn_rcpf(x); }
__device__ __forceinline__ float sigmf(float x) { return rcpf(1.0f + __expf(-x)); }
__device__ __forceinline__ float tanhf_(float x){ return 1.0f - 2.0f * rcpf(__expf(2.0f * x) + 1.0f); }

#define QP_ROT2  0x4E   // quad_perm [2,3,0,1]
#define QP_BC0   0x00   // quad broadcast lane 0
#define QP_BC1   0x55   // quad broadcast lane 1
template<int CTRL>
__device__ __forceinline__ float dppf(float x) {
    return __builtin_bit_cast(float,
        __builtin_amdgcn_update_dpp(0, __builtin_bit_cast(int, x), CTRL, 0xF, 0xF, true));
}

__global__ __launch_bounds__(512, 2) void nnakf_kernel(
    const float* __restrict__ meas,   // [1024][512][2] f32
    const float* __restrict__ Qt,     // [10][4][4]
    const float* __restrict__ Wih,    // [512][2]
    const float* __restrict__ Whh,    // [512][128]
    const float* __restrict__ bih,    // [512]
    const float* __restrict__ bhh,    // [512]
    const float* __restrict__ Wfc,    // [10][128]
    const float* __restrict__ bfc,    // [10]
    float* __restrict__ out)          // [1024][512][4] f32
{
    __shared__ float          meas_s[4 * 1024];   // [b][t*2+c]
    __shared__ unsigned short hbuf[640];          // h bf16, [b] stride 160
    __shared__ float          sig_s[64];          // wave-0 private [q*16+n]
    __shared__ float2         inbuf[4];           // In per batch

    const int tid  = threadIdx.x;
    const int w    = tid >> 6;          // wave 0..7 (0 = Kalman wave)
    const int lane = tid & 63;
    const int idx  = lane & 15;
    const int q    = lane >> 4;         // batch
    const int j    = lane & 3;          // Kalman column (w0 only)
    const int bg0  = blockIdx.x * 4;
    const int hh   = w * 16 + idx;      // this thread's LSTM cell (h index)

    // ---- cooperative meas load ----
    {
        const float4* g4 = (const float4*)(meas + (size_t)bg0 * 1024);
        float4* ms4 = (float4*)meas_s;
        for (int k = tid; k < 1024; k += 512) ms4[k] = g4[k];
    }

    // W_hh B-fragments: tile g covers n = g*128 + hh
    bf16x8 wf[4][4];
    f32x4  biasC[4];
    float2 wihr[4];
    const float4* whh4 = (const float4*)Whh;
    #pragma unroll
    for (int g = 0; g < 4; ++g) {
        const int n = (g << 7) + hh;
        const float bb = bih[n] + bhh[n];
        biasC[g] = (f32x4){bb, bb, bb, bb};
        wihr[g] = ((const float2*)Wih)[n];
        #pragma unroll
        for (int s = 0; s < 4; ++s) {
            float4 u0 = whh4[n * 32 + s * 8 + q * 2];
            float4 u1 = whh4[n * 32 + s * 8 + q * 2 + 1];
            wf[g][s] = cvt8(u0, u1);   // B[k=s*32+q*8+e][n]
        }
    }
    // Kalman-wave weights (used only by w0; uniform init keeps code simple)
    bf16x8 fcf[4];
    #pragma unroll
    for (int s = 0; s < 4; ++s) {
        float4 u0 = make_float4(0.f, 0.f, 0.f, 0.f), u1 = u0;
        if (idx < 10) {
            u0 = ((const float4*)Wfc)[idx * 32 + s * 8 + q * 2];
            u1 = ((const float4*)Wfc)[idx * 32 + s * 8 + q * 2 + 1];
        }
        fcf[s] = cvt8(u0, u1);
    }
    const float bfc_r = (idx < 10) ? bfc[idx] : 0.0f;
    float qreg[10][4];
    #pragma unroll
    for (int n = 0; n < 10; ++n)
        #pragma unroll
        for (int r = 0; r < 4; ++r) qreg[n][r] = Qt[n * 16 + r * 4 + j];

    // ---- persistent state (Kalman parts meaningful on w0 only) ----
    float P0 = (j == 0) ? 1.f : 0.f, P1 = (j == 1) ? 1.f : 0.f;
    float P2 = (j == 2) ? 1.f : 0.f, P3 = (j == 3) ? 1.f : 0.f;
    float x0 = 0.f, x1 = 0.f, x2 = 0.f, x3 = 0.f;
    float cst = 0.f;
    float ppc0, ppc1, ppc2, ppc3, xp0, xp1, inn0, inn1, In0, In1;
    f32x4 acc[4];

    #define PREDICT(TT)                                                          \
    {                                                                            \
        const float fp0 = P0 + DTc * P2, fp1 = P1 + DTc * P3;                    \
        const float d0 = dppf<QP_ROT2>(P0), d1 = dppf<QP_ROT2>(P1);              \
        const float d2 = dppf<QP_ROT2>(P2), d3 = dppf<QP_ROT2>(P3);              \
        const float fq0 = d0 + DTc * d2, fq1 = d1 + DTc * d3;                    \
        const bool jl2 = (j < 2);                                                \
        ppc0 = fp0 + (jl2 ? DTc * fq0 : 0.f) + ((j == 0) ? Q0V : 0.f);           \
        ppc1 = fp1 + (jl2 ? DTc * fq1 : 0.f) + ((j == 1) ? Q0V : 0.f);           \
        ppc2 = P2  + (jl2 ? DTc * d2  : 0.f) + ((j == 2) ? Q0V : 0.f);           \
        ppc3 = P3  + (jl2 ? DTc * d3  : 0.f) + ((j == 3) ? Q0V : 0.f);           \
        xp0 = x0 + DTc * x2; xp1 = x1 + DTc * x3;                                \
        const float2 zz = *(const float2*)&meas_s[q * 1024 + 2 * (TT)];          \
        inn0 = zz.x - xp0; inn1 = zz.y - xp1;                                    \
        const float s000 = dppf<QP_BC0>(ppc0) + RV;                              \
        const float s011 = dppf<QP_BC1>(ppc1) + RV;                              \
        In0 = inn0 * inn0 * rcpf(s000);                                          \
        In1 = inn1 * inn1 * rcpf(s011);                                          \
    }

    __syncthreads();   // meas_s ready

    if (w == 0) {
        PREDICT(0)
        if (idx == 0) inbuf[q] = make_float2(In0, In1);
    }
    #pragma unroll
    for (int g = 0; g < 4; ++g) acc[g] = biasC[g];   // h(-1)=0 -> gates = bias

    __syncthreads();   // inbuf(0) ready

    for (int t = 0; t < 512; ++t) {
        // ======== segment A: pointwise LSTM(t), 1 cell (hh, q) per thread ====
        {
            const float2 inq = inbuf[q];
            float pre[4];
            #pragma unroll
            for (int g = 0; g < 4; ++g)
                pre[g] = acc[g][0] + inq.x * wihr[g].x + inq.y * wihr[g].y;
            const float cn = sigmf(pre[1]) * cst + sigmf(pre[0]) * tanhf_(pre[2]);
            const float hn = sigmf(pre[3]) * tanhf_(cn);
            cst = cn;
            hbuf[q * 160 + hh] = f2bf(hn);
        }
        __syncthreads();   // B1: h(t) published

        // ======== segment B: GEMM everywhere; Kalman tail on w0 only =========
        bf16x8 af[4];
        #pragma unroll
        for (int s = 0; s < 4; ++s)
            af[s] = __builtin_bit_cast(bf16x8,
                        *(const uint4*)&hbuf[(idx >> 2) * 160 + s * 32 + q * 8]);

        if (w == 0) {   // fc GEMM + sigma write first (chain priority)
            f32x4 f0 = (f32x4){0.f, 0.f, 0.f, 0.f};
            f32x4 f1 = (f32x4){0.f, 0.f, 0.f, 0.f};
            f0 = __builtin_amdgcn_mfma_f32_16x16x32_bf16(af[0], fcf[0], f0, 0, 0, 0);
            f1 = __builtin_amdgcn_mfma_f32_16x16x32_bf16(af[1], fcf[1], f1, 0, 0, 0);
            f0 = __builtin_amdgcn_mfma_f32_16x16x32_bf16(af[2], fcf[2], f0, 0, 0, 0);
            f1 = __builtin_amdgcn_mfma_f32_16x16x32_bf16(af[3], fcf[3], f1, 0, 0, 0);
            const f32x4 facc = f0 + f1;
            const float sg = sigmf(facc[0] + bfc_r);   // sigma[batch q][n=idx]
            if (idx < 10) sig_s[q * 16 + idx] = sg;
        }

        // recurrent GEMM(t+1), bias in C of first MFMA (fills w0's sigma RT)
        #pragma unroll
        for (int g = 0; g < 4; ++g)
            acc[g] = __builtin_amdgcn_mfma_f32_16x16x32_bf16(af[0], wf[g][0], biasC[g], 0, 0, 0);
        #pragma unroll
        for (int s = 1; s < 4; ++s)
            #pragma unroll
            for (int g = 0; g < 4; ++g)
                acc[g] = __builtin_amdgcn_mfma_f32_16x16x32_bf16(af[s], wf[g][s], acc[g], 0, 0, 0);

        if (w == 0) {   // sigma read (same-wave DS order) + Qdot + update + predict
            float sn[10];
            #pragma unroll
            for (int n = 0; n < 10; ++n) sn[n] = sig_s[q * 16 + n];
            float a0 = 0.f, a1 = 0.f, a2 = 0.f, a3 = 0.f;
            float e0 = 0.f, e1 = 0.f, e2 = 0.f, e3 = 0.f;
            #pragma unroll
            for (int n = 0; n < 5; ++n) {
                a0 += sn[n] * qreg[n][0]; a1 += sn[n] * qreg[n][1];
                a2 += sn[n] * qreg[n][2]; a3 += sn[n] * qreg[n][3];
            }
            #pragma unroll
            for (int n = 5; n < 10; ++n) {
                e0 += sn[n] * qreg[n][0]; e1 += sn[n] * qreg[n][1];
                e2 += sn[n] * qreg[n][2]; e3 += sn[n] * qreg[n][3];
            }
            const float pc0 = ppc0 + a0 + e0;   // P_pred[:,j]
            const float pc1 = ppc1 + a1 + e1;
            const float pc2 = ppc2 + a2 + e2;
            const float pc3 = ppc3 + a3 + e3;
            const float ph00 = dppf<QP_BC0>(pc0), ph01 = dppf<QP_BC1>(pc0);
            const float ph10 = dppf<QP_BC0>(pc1), ph11 = dppf<QP_BC1>(pc1);
            const float ph20 = dppf<QP_BC0>(pc2), ph21 = dppf<QP_BC1>(pc2);
            const float ph30 = dppf<QP_BC0>(pc3), ph31 = dppf<QP_BC1>(pc3);
            const float s00 = ph00 + RV, s01 = ph01, s10 = ph10, s11 = ph11 + RV;
            const float rdet = rcpf(s00 * s11 - s01 * s10);
            const float u0 = rdet * (s11 * inn0 - s01 * inn1);
            const float u1 = rdet * (s00 * inn1 - s10 * inn0);
            x0 = xp0 + ph00 * u0 + ph01 * u1;
            x1 = xp1 + ph10 * u0 + ph11 * u1;
            x2 = x2  + ph20 * u0 + ph21 * u1;
            x3 = x3  + ph30 * u0 + ph31 * u1;
            const float w0r = rdet * (s11 * pc0 - s01 * pc1);
            const float w1r = rdet * (s00 * pc1 - s10 * pc0);
            P0 = pc0 - ph00 * w0r - ph01 * w1r;
            P1 = pc1 - ph10 * w0r - ph11 * w1r;
            P2 = pc2 - ph20 * w0r - ph21 * w1r;
            P3 = pc3 - ph30 * w0r - ph31 * w1r;
            if (idx == 0) {
                float4* o = (float4*)out;
                o[(size_t)(bg0 + q) * 512 + t] = make_float4(x0, x1, x2, x3);
            }
            const int tn = (t < 511) ? t + 1 : 511;
            PREDICT(tn)
            if (idx == 0) inbuf[q] = make_float2(In0, In1);
        }
        __syncthreads();   // B2: In(t+1) published; hbuf free for rewrite
    }
}

extern "C" void kernel_launch(void* const* d_in, const int* in_sizes, int n_in,
                              void* d_out, int out_size, void* d_ws, size_t ws_size,
                              hipStream_t stream) {
    (void)in_sizes; (void)n_in; (void)out_size; (void)d_ws; (void)ws_size;
    nnakf_kernel<<<256, 512, 0, stream>>>(
        (const float*)d_in[0],  // measurements
        (const float*)d_in[1],  // Q_tilde
        (const float*)d_in[2],  // W_ih
        (const float*)d_in[3],  // W_hh
        (const float*)d_in[4],  // b_ih
        (const float*)d_in[5],  // b_hh
        (const float*)d_in[6],  // W_fc
        (const float*)d_in[7],  // b_fc
        (float*)d_out);
}